// Round 13
// baseline (176.939 us; speedup 1.0000x reference)
//
#include <hip/hip_runtime.h>
#include <hip/hip_fp16.h>
#include <math.h>
#include <float.h>

#define M_G 100000
#define M_PAD 100032         // 1563 * 64
#define NT64 1563            // 64-row gallery tiles
#define N_Q 2048
#define DIM 256
#define NG 3126              // 32-row groups = NT64*2
#define GSTR 3136            // padded group stride (halves) per query row
#define MARGIN 0.009f        // 2*(2^-11 RN) fp16 dot bound + fp16-bmax quant + slack

typedef _Float16 f16x8 __attribute__((ext_vector_type(8)));
typedef float f32x16 __attribute__((ext_vector_type(16)));

// ws layout (bytes)
#define WS_GP 0                        // 1563 * 32768 = 51,216,384
#define WS_QP 51216384                 // 8 * 131072   =  1,048,576
#define WS_BM 52264960                 // 2048*3136*2  = 12,845,056

__device__ inline unsigned pack_h2(float a, float b) {
    __half ha = __float2half(a), hb = __float2half(b);   // RN
    return (unsigned)*(unsigned short*)&ha | ((unsigned)*(unsigned short*)&hb << 16);
}
__device__ inline void gload_lds16(const void* gsrc, void* ldst) {
    __builtin_amdgcn_global_load_lds(
        (const __attribute__((address_space(1))) unsigned int*)gsrc,
        (__attribute__((address_space(3))) unsigned int*)ldst, 16, 0, 0);
}

#define BAR __builtin_amdgcn_s_barrier()
#define LGKM0 { asm volatile("s_waitcnt lgkmcnt(0)" ::: "memory"); \
                __builtin_amdgcn_sched_barrier(0); }
#define LGKM4 { asm volatile("s_waitcnt lgkmcnt(4)" ::: "memory"); \
                __builtin_amdgcn_sched_barrier(0); }
#define VMCNT(n) { asm volatile("s_waitcnt vmcnt(" #n ")" ::: "memory"); \
                   __builtin_amdgcn_sched_barrier(0); }

// Normalize rows, fp32->fp16 (RN), store swizzled LDS-image layout.
// Gallery: 64-row tiles; chunk (mt64*4+kt) of 512 uint4; granule (rl∈[0,64),gg)
// at rl*8 + (gg ^ (rl&7)). Queries: 256-row tiles; chunk (qt*4+kt) of 2048
// uint4, rl∈[0,256). Gallery pad rows (>=M_G) zeroed.
__global__ __launch_bounds__(256) void pack_kernel(
    const float* __restrict__ g, const float* __restrict__ q,
    uint4* __restrict__ gp, uint4* __restrict__ qp)
{
    const int b = blockIdx.x;
    const int w4 = threadIdx.x >> 6, lane = threadIdx.x & 63;
    const bool isg = b < (M_PAD / 4);
    const int row = (isg ? b : b - M_PAD / 4) * 4 + w4;
    const bool real = !isg || row < M_G;
    const float* src = isg ? g + (size_t)row * DIM : q + (size_t)row * DIM;

    float inv = 0.0f;
    if (real) {
        float4 v = ((const float4*)src)[lane];
        float ss = v.x * v.x + v.y * v.y + v.z * v.z + v.w * v.w;
        #pragma unroll
        for (int o = 32; o; o >>= 1) ss += __shfl_xor(ss, o);
        inv = 1.0f / fmaxf(sqrtf(ss), 1e-12f);
    }
    if (lane < 32) {
        uint4 w = make_uint4(0u, 0u, 0u, 0u);
        if (real) {
            float4 a = ((const float4*)src)[lane * 2];
            float4 c = ((const float4*)src)[lane * 2 + 1];
            w.x = pack_h2(a.x * inv, a.y * inv);
            w.y = pack_h2(a.z * inv, a.w * inv);
            w.z = pack_h2(c.x * inv, c.y * inv);
            w.w = pack_h2(c.z * inv, c.w * inv);
        }
        const int kt = lane >> 3, gg = lane & 7;
        if (isg) {
            int mt = row >> 6, rl = row & 63;
            gp[((size_t)mt * 4 + kt) * 512 + rl * 8 + (gg ^ (rl & 7))] = w;
        } else {
            int qt = row >> 8, rl = row & 255;
            qp[((size_t)qt * 4 + kt) * 2048 + rl * 8 + (gg ^ (rl & 7))] = w;
        }
    }
}

// stage 32KB (2048 uint4) with 512 threads: 4 issues/thread
#define STAGE32(dstbase, src) { const uint4* s_ = (src); _Pragma("unroll") \
  for (int p_ = 0; p_ < 4; ++p_) \
    gload_lds16(s_ + p_ * 512 + tid, lds + (dstbase) + (p_ * 512 + tid) * 16); }

// one quarter of the stage (phase-distributed)
#define STAGE_P(dstbase, src, P) { const uint4* s_ = (src); \
    gload_lds16(s_ + (P) * 512 + tid, lds + (dstbase) + ((P) * 512 + tid) * 16); }

// B (query) fragments for one kt (4 k-steps x 2 col-blocks), 8 ds_read_b128
#define READ_BQ(KT, bufbase) { _Pragma("unroll") \
  for (int sl_ = 0; sl_ < 4; ++sl_) { _Pragma("unroll") \
    for (int cb_ = 0; cb_ < 2; ++cb_) \
      bR[(KT) * 4 + sl_][cb_] = *(const f16x8*)(lds + (bufbase) + qroff + \
          cb_ * 4096 + ((((sl_ << 1) + lh) ^ l7) << 4)); } }

// A (gallery) fragment for k-step S from current tile buffer base pb
#define RD_A(S) (*(const f16x8*)(pb + ((S) >> 2) * 8192 + \
    ((((((S) & 3) << 1) + lh) ^ l7) << 4)))

#define MFMA32(AV, S) { \
    acc[0] = __builtin_amdgcn_mfma_f32_32x32x16_f16(AV, bR[S][0], acc[0], 0, 0, 0); \
    acc[1] = __builtin_amdgcn_mfma_f32_32x32x16_f16(AV, bR[S][1], acc[1], 0, 0, 0); }
#define MFMB32(AV, S) { \
    accb[0] = __builtin_amdgcn_mfma_f32_32x32x16_f16(AV, bR[S][0], accb[0], 0, 0, 0); \
    accb[1] = __builtin_amdgcn_mfma_f32_32x32x16_f16(AV, bR[S][1], accb[1], 0, 0, 0); }

// Phase A: Q-stationary M-streaming fp16 MFMA, 32x32x16 shape, with the
// guide's phase template (T3+T4+T5) ported to the M-streaming loop: each
// 64-row tile = 4 phases of {issue next phase's 4 ds_read + 1/4 of next
// tile's stage -> BAR -> counted lgkmcnt(4) -> setprio(1) 8 MFMAs setprio(0)
// -> BAR}. Reads for phase p+1 fly under phase p's MFMAs; counted vmcnt(2)
// at iter end (4 loads retire in order ahead of the 2 epilogue stores).
__global__ __launch_bounds__(512, 2) void scoreA_kernel(
    const uint4* __restrict__ gp, const uint4* __restrict__ qp,
    unsigned short* __restrict__ bmaxH)
{
    extern __shared__ char lds[];   // 65536: buf0 [0,32K) | buf1 [32K,64K)

    const int bid = blockIdx.x;
    const int xcd = bid & 7;
    const int qt = (bid >> 3) & 7;
    const int mc = (bid >> 6) * 8 + xcd;             // 64 chunks of 24-25 tiles
    const int nt = (mc < 27) ? 25 : 24;
    const int t0 = (mc < 27) ? mc * 25 : 675 + (mc - 27) * 24;

    const int tid = threadIdx.x;
    const int wid = tid >> 6, lane = tid & 63;
    const int wr = wid >> 2, wc = wid & 3;          // 2m x 4n wave grid
    const int l31 = lane & 31, lh = lane >> 5, l7 = lane & 7;
    const int qroff = (wc * 64 + l31) * 128;        // B-frag row base (cb adds 4096)
    const int aroff = (wr * 32 + l31) * 128;        // A-frag row base

    const uint4* qsrc = qp + (size_t)qt * 8192;

    // ---- prologue: all 32 B-fragments -> registers via alternating bufs ----
    f16x8 bR[16][2];
    STAGE32(0,     qsrc + 0 * 2048);
    STAGE32(32768, qsrc + 1 * 2048);
    VMCNT(4); BAR;                    // kt0 ready
    READ_BQ(0, 0); LGKM0; BAR;
    STAGE32(0, qsrc + 2 * 2048);
    VMCNT(4); BAR;                    // kt1 ready
    READ_BQ(1, 32768); LGKM0; BAR;
    STAGE32(32768, qsrc + 3 * 2048);
    VMCNT(4); BAR;                    // kt2 ready
    READ_BQ(2, 0); LGKM0; BAR;
    STAGE32(0, gp + (size_t)t0 * 2048);
    VMCNT(4); BAR;                    // kt3 ready
    READ_BQ(3, 32768); LGKM0; BAR;
    VMCNT(0); BAR;                    // gallery tile t0 ready in buf0

    // ---- main loop: stream 64-row gallery tiles, 4 phases per tile ----
    for (int t = 0; t < nt; ++t) {
        const int mtile = t0 + t;
        const int cur = (t & 1) << 15;
        const int nxt = cur ^ 32768;
        const uint4* nsrc = gp + (size_t)(mtile + 1) * 2048;
        const bool pf = (t + 1 < nt);

        f32x16 acc[2], accb[2];
        #pragma unroll
        for (int c = 0; c < 2; ++c)
            #pragma unroll
            for (int i = 0; i < 16; ++i) { acc[c][i] = 0.f; accb[c][i] = 0.f; }

        const char* pb = lds + cur + aroff;
        f16x8 pA0, pA1, pA2, pA3;     // current-phase fragments
        f16x8 pN0, pN1, pN2, pN3;     // next-phase fragments

        // phase 0 reads (S0..3)
        pA0 = RD_A(0);  pA1 = RD_A(1);  pA2 = RD_A(2);  pA3 = RD_A(3);

        // ---- phase 0: compute S0..3, read S4..7, stage part 0 ----
        pN0 = RD_A(4);  pN1 = RD_A(5);  pN2 = RD_A(6);  pN3 = RD_A(7);
        if (pf) STAGE_P(nxt, nsrc, 0);
        BAR; LGKM4;
        __builtin_amdgcn_s_setprio(1);
        MFMA32(pA0, 0); MFMB32(pA1, 1); MFMA32(pA2, 2); MFMB32(pA3, 3);
        __builtin_amdgcn_s_setprio(0);
        BAR;
        // ---- phase 1: compute S4..7, read S8..11, stage part 1 ----
        pA0 = RD_A(8);  pA1 = RD_A(9);  pA2 = RD_A(10); pA3 = RD_A(11);
        if (pf) STAGE_P(nxt, nsrc, 1);
        BAR; LGKM4;
        __builtin_amdgcn_s_setprio(1);
        MFMA32(pN0, 4); MFMB32(pN1, 5); MFMA32(pN2, 6); MFMB32(pN3, 7);
        __builtin_amdgcn_s_setprio(0);
        BAR;
        // ---- phase 2: compute S8..11, read S12..15, stage part 2 ----
        pN0 = RD_A(12); pN1 = RD_A(13); pN2 = RD_A(14); pN3 = RD_A(15);
        if (pf) STAGE_P(nxt, nsrc, 2);
        BAR; LGKM4;
        __builtin_amdgcn_s_setprio(1);
        MFMA32(pA0, 8); MFMB32(pA1, 9); MFMA32(pA2, 10); MFMB32(pA3, 11);
        __builtin_amdgcn_s_setprio(0);
        BAR;
        // ---- phase 3: compute S12..15, stage part 3 (no reads) ----
        if (pf) STAGE_P(nxt, nsrc, 3);
        BAR; LGKM0;
        __builtin_amdgcn_s_setprio(1);
        MFMA32(pN0, 12); MFMB32(pN1, 13); MFMA32(pN2, 14); MFMB32(pN3, 15);
        __builtin_amdgcn_s_setprio(0);
        BAR;

        // epilogue: per-q max over this wave's 32-row group
        const int group = mtile * 2 + wr;
        const bool padgrp = (mtile * 64 + wr * 32) >= M_G;
        #pragma unroll
        for (int cb = 0; cb < 2; ++cb) {
            f32x16 f = acc[cb] + accb[cb];
            float m0 = fmaxf(fmaxf(fmaxf(f[0], f[1]), fmaxf(f[2], f[3])),
                             fmaxf(fmaxf(f[4], f[5]), fmaxf(f[6], f[7])));
            float m1 = fmaxf(fmaxf(fmaxf(f[8], f[9]), fmaxf(f[10], f[11])),
                             fmaxf(fmaxf(f[12], f[13]), fmaxf(f[14], f[15])));
            float v = fmaxf(m0, m1);
            v = fmaxf(v, __shfl_xor(v, 32));     // combine row-halves
            if (lane < 32) {
                int qn = qt * 256 + wc * 64 + cb * 32 + l31;
                __half h = __float2half(padgrp ? -65504.f : v);
                bmaxH[(size_t)qn * GSTR + group] = *(unsigned short*)&h;
            }
        }
        // outstanding: 4 stage loads (oldest, in-order retire) + 2 stores ->
        // VMCNT(2) waits exactly for the loads.
        if (pf) { VMCNT(2); BAR; }
    }
}

// Phase B: s1 scan + candidate collection (32-row groups, fp16 bmax) + exact
// fp32 rescore with recomputed norms; tie-break = lowest index (np.argmax).
__global__ __launch_bounds__(256) void phaseB_kernel(
    const float* __restrict__ q, const float* __restrict__ g,
    const unsigned short* __restrict__ bmaxH,
    const int* __restrict__ cat, const int* __restrict__ shp,
    int* __restrict__ out)
{
    __shared__ __align__(16) float qrow[DIM];
    __shared__ int glist[NG];
    __shared__ int ng;
    __shared__ float smax[4];
    __shared__ float rbs[4];
    __shared__ int rbi[4];

    const int qi = blockIdx.x;
    const int tid = threadIdx.x;
    const int lane = tid & 63, wid = tid >> 6;
    const __half* bm = (const __half*)(bmaxH + (size_t)qi * GSTR);
    if (tid < 64)
        *(float4*)&qrow[tid * 4] = *(const float4*)(q + (size_t)qi * DIM + tid * 4);
    if (tid == 0) ng = 0;

    float m = -FLT_MAX;
    for (int gr = tid; gr < NG; gr += 256)
        m = fmaxf(m, __half2float(bm[gr]));
    #pragma unroll
    for (int o = 32; o; o >>= 1) m = fmaxf(m, __shfl_xor(m, o));
    if (lane == 0) smax[wid] = m;
    __syncthreads();
    const float thr = fmaxf(fmaxf(smax[0], smax[1]), fmaxf(smax[2], smax[3])) - MARGIN;

    for (int gr = tid; gr < NG; gr += 256)
        if (__half2float(bm[gr]) >= thr)
            glist[atomicAdd(&ng, 1)] = gr;
    __syncthreads();

    float bs = -FLT_MAX;
    int bi = 0x7fffffff;
    const int r = tid >> 3, p = tid & 7;    // 32 rows x 8 dim-slices
    const int n = ng;
    for (int i = 0; i < n; ++i) {
        int mm = glist[i] * 32 + r;
        if (mm < M_G) {
            const float* grow = g + (size_t)mm * DIM + p * 32;
            const float* qr = qrow + p * 32;
            float s = 0.f, ssq = 0.f;
            #pragma unroll
            for (int jj = 0; jj < 8; ++jj) {
                float4 gv = *(const float4*)(grow + jj * 4);
                float4 qv = *(const float4*)(qr + jj * 4);
                s += gv.x * qv.x + gv.y * qv.y + gv.z * qv.z + gv.w * qv.w;
                ssq += gv.x * gv.x + gv.y * gv.y + gv.z * gv.z + gv.w * gv.w;
            }
            s += __shfl_xor(s, 1);  s += __shfl_xor(s, 2);  s += __shfl_xor(s, 4);
            ssq += __shfl_xor(ssq, 1); ssq += __shfl_xor(ssq, 2); ssq += __shfl_xor(ssq, 4);
            s *= 1.0f / fmaxf(sqrtf(ssq), 1e-12f);
            if (p == 0 && (s > bs || (s == bs && mm < bi))) { bs = s; bi = mm; }
        }
    }
    #pragma unroll
    for (int o = 1; o < 64; o <<= 1) {
        float os = __shfl_xor(bs, o);
        int oi = __shfl_xor(bi, o);
        if (os > bs || (os == bs && oi < bi)) { bs = os; bi = oi; }
    }
    if (lane == 0) { rbs[wid] = bs; rbi[wid] = bi; }
    __syncthreads();
    if (tid == 0) {
        #pragma unroll
        for (int ww = 1; ww < 4; ++ww)
            if (rbs[ww] > bs || (rbs[ww] == bs && rbi[ww] < bi)) { bs = rbs[ww]; bi = rbi[ww]; }
        out[qi] = cat[bi];
        out[N_Q + qi] = shp[bi];
    }
}

extern "C" void kernel_launch(void* const* d_in, const int* in_sizes, int n_in,
                              void* d_out, int out_size, void* d_ws, size_t ws_size,
                              hipStream_t stream) {
    const float* q = (const float*)d_in[0];    // [2048,256] fp32
    const float* g = (const float*)d_in[1];    // [100000,256] fp32
    const int* cat = (const int*)d_in[2];      // [100000] int32
    const int* shp = (const int*)d_in[3];      // [100000] int32
    int* out = (int*)d_out;                    // [2048 cat | 2048 shape] int32

    char* ws = (char*)d_ws;
    uint4* gp             = (uint4*)(ws + WS_GP);
    uint4* qp             = (uint4*)(ws + WS_QP);
    unsigned short* bmaxH = (unsigned short*)(ws + WS_BM);

    hipFuncSetAttribute((const void*)scoreA_kernel,
                        hipFuncAttributeMaxDynamicSharedMemorySize, 65536);

    pack_kernel<<<M_PAD / 4 + N_Q / 4, 256, 0, stream>>>(g, q, gp, qp);
    scoreA_kernel<<<512, 512, 65536, stream>>>(gp, qp, bmaxH);
    phaseB_kernel<<<N_Q, 256, 0, stream>>>(q, g, bmaxH, cat, shp, out);
}

// Round 14
// 174.676 us; speedup vs baseline: 1.0130x; 1.0130x over previous
//
#include <hip/hip_runtime.h>
#include <hip/hip_fp16.h>
#include <math.h>
#include <float.h>

#define M_G 100000
#define M_PAD 100032         // 1563 * 64
#define NT64 1563            // 64-row gallery tiles
#define N_Q 2048
#define DIM 256
#define NG 3126              // 32-row groups = NT64*2
#define GSTR 3136            // padded group stride (halves) per query row
#define MARGIN 0.009f        // 2*(2^-11 RN) fp16 dot bound + fp16-bmax quant + slack

typedef _Float16 f16x8 __attribute__((ext_vector_type(8)));
typedef float f32x4 __attribute__((ext_vector_type(4)));

// ws layout (bytes)
#define WS_GP 0                        // 1563 * 32768 = 51,216,384
#define WS_QP 51216384                 // 8 * 131072   =  1,048,576
#define WS_BM 52264960                 // 2048*3136*2  = 12,845,056

__device__ inline unsigned pack_h2(float a, float b) {
    __half ha = __float2half(a), hb = __float2half(b);   // RN
    return (unsigned)*(unsigned short*)&ha | ((unsigned)*(unsigned short*)&hb << 16);
}
__device__ inline void gload_lds16(const void* gsrc, void* ldst) {
    __builtin_amdgcn_global_load_lds(
        (const __attribute__((address_space(1))) unsigned int*)gsrc,
        (__attribute__((address_space(3))) unsigned int*)ldst, 16, 0, 0);
}

#define BAR __builtin_amdgcn_s_barrier()
#define LGKM0 { asm volatile("s_waitcnt lgkmcnt(0)" ::: "memory"); \
                __builtin_amdgcn_sched_barrier(0); }
#define VMCNT(n) { asm volatile("s_waitcnt vmcnt(" #n ")" ::: "memory"); \
                   __builtin_amdgcn_sched_barrier(0); }

// Normalize rows, fp32->fp16 (RN), store swizzled LDS-image layout.
// Gallery: 64-row tiles; chunk (mt64*4+kt) of 512 uint4; granule (rl∈[0,64),gg)
// at rl*8 + (gg ^ (rl&7)). Queries: 256-row tiles; chunk (qt*4+kt) of 2048
// uint4, rl∈[0,256). Gallery pad rows (>=M_G) zeroed.
__global__ __launch_bounds__(256) void pack_kernel(
    const float* __restrict__ g, const float* __restrict__ q,
    uint4* __restrict__ gp, uint4* __restrict__ qp)
{
    const int b = blockIdx.x;
    const int w4 = threadIdx.x >> 6, lane = threadIdx.x & 63;
    const bool isg = b < (M_PAD / 4);
    const int row = (isg ? b : b - M_PAD / 4) * 4 + w4;
    const bool real = !isg || row < M_G;
    const float* src = isg ? g + (size_t)row * DIM : q + (size_t)row * DIM;

    float inv = 0.0f;
    if (real) {
        float4 v = ((const float4*)src)[lane];
        float ss = v.x * v.x + v.y * v.y + v.z * v.z + v.w * v.w;
        #pragma unroll
        for (int o = 32; o; o >>= 1) ss += __shfl_xor(ss, o);
        inv = 1.0f / fmaxf(sqrtf(ss), 1e-12f);
    }
    if (lane < 32) {
        uint4 w = make_uint4(0u, 0u, 0u, 0u);
        if (real) {
            float4 a = ((const float4*)src)[lane * 2];
            float4 c = ((const float4*)src)[lane * 2 + 1];
            w.x = pack_h2(a.x * inv, a.y * inv);
            w.y = pack_h2(a.z * inv, a.w * inv);
            w.z = pack_h2(c.x * inv, c.y * inv);
            w.w = pack_h2(c.z * inv, c.w * inv);
        }
        const int kt = lane >> 3, gg = lane & 7;
        if (isg) {
            int mt = row >> 6, rl = row & 63;
            gp[((size_t)mt * 4 + kt) * 512 + rl * 8 + (gg ^ (rl & 7))] = w;
        } else {
            int qt = row >> 8, rl = row & 255;
            qp[((size_t)qt * 4 + kt) * 2048 + rl * 8 + (gg ^ (rl & 7))] = w;
        }
    }
}

// block-wide stage of a 32KB query chunk (2048 uint4), 512 thr: 4 issues each
#define STAGE32(dstbase, src) { const uint4* s_ = (src); _Pragma("unroll") \
  for (int p_ = 0; p_ < 4; ++p_) \
    gload_lds16(s_ + p_ * 512 + tid, lds + (dstbase) + (p_ * 512 + tid) * 16); }

// wave-private stage: quarter KT of gallery tile (src base ts), 4 issues/lane
#define STAGE_Q(ts, KT) { const uint4* s_ = (ts) + (KT) * 512 + wr * 256; \
  _Pragma("unroll") for (int p_ = 0; p_ < 4; ++p_) \
    gload_lds16(s_ + p_ * 64 + lane, myr + (KT) * 4096 + (p_ * 64 + lane) * 16); }

// B (query) fragments for one kt: 8 ds_read_b128 into bR[KT]
#define READ_BP(KT, bufbase) { _Pragma("unroll") \
  for (int nj = 0; nj < 4; ++nj) { \
    const char* p_ = lds + (bufbase) + (wc * 64 + nj * 16 + r16) * 128; \
    bR[KT][0][nj] = *(const f16x8*)(p_ + sw0); \
    bR[KT][1][nj] = *(const f16x8*)(p_ + sw1); } }

// A (gallery) fragment from my private region: quarter KT, half KK, frag F
#define RD_AQ(KT, KK, F) \
    (*(const f16x8*)(myr + (KT) * 4096 + ((F) * 16 + r16) * 128 + ((KK) ? sw1 : sw0)))

#define MFMA8(A0, A1, KT, KK) { _Pragma("unroll") \
  for (int nj = 0; nj < 4; ++nj) { \
    acc[0][nj] = __builtin_amdgcn_mfma_f32_16x16x32_f16( \
        A0, bR[KT][KK][nj], acc[0][nj], 0, 0, 0); \
    acc[1][nj] = __builtin_amdgcn_mfma_f32_16x16x32_f16( \
        A1, bR[KT][KK][nj], acc[1][nj], 0, 0, 0); } }

// Phase A: BARRIER-FREE wave-private M-streaming fp16 MFMA. 512 blocks
// (8 qt x 64 mchunks, XCD-chunked), 512 thr = 8 waves (2m x 4n). Each wave
// owns a PRIVATE 16KB LDS region (8x16KB = 128KB) holding its 32 gallery
// rows x 256 k; it stages its own copy (same-row waves hit L1, so L2/HBM
// traffic is unchanged). Main loop has ZERO barriers: per k-quarter
// {4 ds_read -> lgkmcnt(0) -> issue quarter's 4 gload_lds for t+1 -> 16
// MFMA}; per-wave counted VMCNT(4) at iter end (16 loads retire in order
// ahead of the 4 epilogue stores). The 2 waves/SIMD free-run and cover each
// other's waits (m114 co-schedule) -- no block-lockstep serialization.
__global__ __launch_bounds__(512, 2) void scoreA_kernel(
    const uint4* __restrict__ gp, const uint4* __restrict__ qp,
    unsigned short* __restrict__ bmaxH)
{
    extern __shared__ char lds[];   // 131072 = 8 x 16KB wave-private regions

    const int bid = blockIdx.x;
    const int xcd = bid & 7;
    const int qt = (bid >> 3) & 7;
    const int mc = (bid >> 6) * 8 + xcd;             // 64 chunks of 24-25 tiles
    const int nt = (mc < 27) ? 25 : 24;
    const int t0 = (mc < 27) ? mc * 25 : 675 + (mc - 27) * 24;

    const int tid = threadIdx.x;
    const int wid = tid >> 6, lane = tid & 63;
    const int wr = wid >> 2, wc = wid & 3;          // 2m x 4n wave grid
    const int r16 = lane & 15, rhi = lane >> 4;
    const int sw0 = ((rhi ^ (r16 & 7)) << 4);       // k-granule swizzle, kk=0
    const int sw1 = (((4 + rhi) ^ (r16 & 7)) << 4); // kk=1
    char* myr = lds + wid * 16384;                  // my private region

    const uint4* qsrc = qp + (size_t)qt * 8192;

    // ---- prologue: all B (query) fragments -> registers (block-wide) ----
    f16x8 bR[4][2][4];
    STAGE32(0,     qsrc + 0 * 2048);
    STAGE32(32768, qsrc + 1 * 2048);
    VMCNT(4); BAR;                    // kt0 ready
    READ_BP(0, 0); LGKM0; BAR;
    STAGE32(0, qsrc + 2 * 2048);
    VMCNT(4); BAR;                    // kt1 ready (older loads drained)
    READ_BP(1, 32768); LGKM0; BAR;
    STAGE32(32768, qsrc + 3 * 2048);
    VMCNT(4); BAR;                    // kt2 ready
    READ_BP(2, 0); LGKM0; BAR;
    VMCNT(0); BAR;                    // kt3 ready
    READ_BP(3, 32768); LGKM0; BAR;    // last block-wide barrier

    // stage my first gallery tile into my private region
    {
        const uint4* ts = gp + (size_t)t0 * 2048;
        STAGE_Q(ts, 0); STAGE_Q(ts, 1); STAGE_Q(ts, 2); STAGE_Q(ts, 3);
    }
    VMCNT(0);

    // ---- main loop: stream 64-row gallery tiles, no barriers ----
    for (int t = 0; t < nt; ++t) {
        const int mtile = t0 + t;
        const bool pf = (t + 1 < nt);
        const uint4* nsrc = gp + (size_t)(mtile + 1) * 2048;

        f32x4 acc[2][4];
        #pragma unroll
        for (int mi = 0; mi < 2; ++mi)
            #pragma unroll
            for (int nj = 0; nj < 4; ++nj) acc[mi][nj] = (f32x4){0.f, 0.f, 0.f, 0.f};

        #pragma unroll
        for (int kt = 0; kt < 4; ++kt) {
            f16x8 a00 = RD_AQ(kt, 0, 0), a01 = RD_AQ(kt, 0, 1);
            f16x8 a10 = RD_AQ(kt, 1, 0), a11 = RD_AQ(kt, 1, 1);
            LGKM0;                       // my reads of quarter kt complete
            if (pf) STAGE_Q(nsrc, kt);   // safe: quarter kt fully consumed
            MFMA8(a00, a01, kt, 0);
            MFMA8(a10, a11, kt, 1);
        }

        // epilogue: per-q max over this wave's 32-row group
        float cm[4] = {-FLT_MAX, -FLT_MAX, -FLT_MAX, -FLT_MAX};
        #pragma unroll
        for (int mi = 0; mi < 2; ++mi)
            #pragma unroll
            for (int jj = 0; jj < 4; ++jj)
                #pragma unroll
                for (int nj = 0; nj < 4; ++nj)
                    cm[nj] = fmaxf(cm[nj], acc[mi][nj][jj]);
        const int group = mtile * 2 + wr;
        const bool padgrp = (mtile * 64 + wr * 32) >= M_G;
        #pragma unroll
        for (int nj = 0; nj < 4; ++nj) {
            float v = cm[nj];
            v = fmaxf(v, __shfl_xor(v, 16));
            v = fmaxf(v, __shfl_xor(v, 32));
            if (lane < 16) {
                int qn = qt * 256 + wc * 64 + nj * 16 + lane;
                __half h = __float2half(padgrp ? -65504.f : v);
                bmaxH[(size_t)qn * GSTR + group] = *(unsigned short*)&h;
            }
        }
        // outstanding per wave: 16 loads (oldest, in-order) + 4 stores ->
        // VMCNT(4) waits exactly for the loads.
        if (pf) { VMCNT(4); }
    }
}

// Phase B: s1 scan + candidate collection (32-row groups, fp16 bmax) + exact
// fp32 rescore with recomputed norms; tie-break = lowest index (np.argmax).
__global__ __launch_bounds__(256) void phaseB_kernel(
    const float* __restrict__ q, const float* __restrict__ g,
    const unsigned short* __restrict__ bmaxH,
    const int* __restrict__ cat, const int* __restrict__ shp,
    int* __restrict__ out)
{
    __shared__ __align__(16) float qrow[DIM];
    __shared__ int glist[NG];
    __shared__ int ng;
    __shared__ float smax[4];
    __shared__ float rbs[4];
    __shared__ int rbi[4];

    const int qi = blockIdx.x;
    const int tid = threadIdx.x;
    const int lane = tid & 63, wid = tid >> 6;
    const __half* bm = (const __half*)(bmaxH + (size_t)qi * GSTR);
    if (tid < 64)
        *(float4*)&qrow[tid * 4] = *(const float4*)(q + (size_t)qi * DIM + tid * 4);
    if (tid == 0) ng = 0;

    float m = -FLT_MAX;
    for (int gr = tid; gr < NG; gr += 256)
        m = fmaxf(m, __half2float(bm[gr]));
    #pragma unroll
    for (int o = 32; o; o >>= 1) m = fmaxf(m, __shfl_xor(m, o));
    if (lane == 0) smax[wid] = m;
    __syncthreads();
    const float thr = fmaxf(fmaxf(smax[0], smax[1]), fmaxf(smax[2], smax[3])) - MARGIN;

    for (int gr = tid; gr < NG; gr += 256)
        if (__half2float(bm[gr]) >= thr)
            glist[atomicAdd(&ng, 1)] = gr;
    __syncthreads();

    float bs = -FLT_MAX;
    int bi = 0x7fffffff;
    const int r = tid >> 3, p = tid & 7;    // 32 rows x 8 dim-slices
    const int n = ng;
    for (int i = 0; i < n; ++i) {
        int mm = glist[i] * 32 + r;
        if (mm < M_G) {
            const float* grow = g + (size_t)mm * DIM + p * 32;
            const float* qr = qrow + p * 32;
            float s = 0.f, ssq = 0.f;
            #pragma unroll
            for (int jj = 0; jj < 8; ++jj) {
                float4 gv = *(const float4*)(grow + jj * 4);
                float4 qv = *(const float4*)(qr + jj * 4);
                s += gv.x * qv.x + gv.y * qv.y + gv.z * qv.z + gv.w * qv.w;
                ssq += gv.x * gv.x + gv.y * gv.y + gv.z * gv.z + gv.w * gv.w;
            }
            s += __shfl_xor(s, 1);  s += __shfl_xor(s, 2);  s += __shfl_xor(s, 4);
            ssq += __shfl_xor(ssq, 1); ssq += __shfl_xor(ssq, 2); ssq += __shfl_xor(ssq, 4);
            s *= 1.0f / fmaxf(sqrtf(ssq), 1e-12f);
            if (p == 0 && (s > bs || (s == bs && mm < bi))) { bs = s; bi = mm; }
        }
    }
    #pragma unroll
    for (int o = 1; o < 64; o <<= 1) {
        float os = __shfl_xor(bs, o);
        int oi = __shfl_xor(bi, o);
        if (os > bs || (os == bs && oi < bi)) { bs = os; bi = oi; }
    }
    if (lane == 0) { rbs[wid] = bs; rbi[wid] = bi; }
    __syncthreads();
    if (tid == 0) {
        #pragma unroll
        for (int ww = 1; ww < 4; ++ww)
            if (rbs[ww] > bs || (rbs[ww] == bs && rbi[ww] < bi)) { bs = rbs[ww]; bi = rbi[ww]; }
        out[qi] = cat[bi];
        out[N_Q + qi] = shp[bi];
    }
}

extern "C" void kernel_launch(void* const* d_in, const int* in_sizes, int n_in,
                              void* d_out, int out_size, void* d_ws, size_t ws_size,
                              hipStream_t stream) {
    const float* q = (const float*)d_in[0];    // [2048,256] fp32
    const float* g = (const float*)d_in[1];    // [100000,256] fp32
    const int* cat = (const int*)d_in[2];      // [100000] int32
    const int* shp = (const int*)d_in[3];      // [100000] int32
    int* out = (int*)d_out;                    // [2048 cat | 2048 shape] int32

    char* ws = (char*)d_ws;
    uint4* gp             = (uint4*)(ws + WS_GP);
    uint4* qp             = (uint4*)(ws + WS_QP);
    unsigned short* bmaxH = (unsigned short*)(ws + WS_BM);

    hipFuncSetAttribute((const void*)scoreA_kernel,
                        hipFuncAttributeMaxDynamicSharedMemorySize, 131072);

    pack_kernel<<<M_PAD / 4 + N_Q / 4, 256, 0, stream>>>(g, q, gp, qp);
    scoreA_kernel<<<512, 512, 131072, stream>>>(gp, qp, bmaxH);
    phaseB_kernel<<<N_Q, 256, 0, stream>>>(q, g, bmaxH, cat, shp, out);
}

// Round 15
// 159.986 us; speedup vs baseline: 1.1060x; 1.0918x over previous
//
#include <hip/hip_runtime.h>
#include <hip/hip_fp16.h>
#include <math.h>
#include <float.h>

#define M_G 100000
#define M_PAD 100032         // 1563 * 64
#define NT64 1563            // 64-row gallery tiles
#define N_Q 2048
#define DIM 256
#define NG 3126              // 32-row groups = NT64*2
#define GSTR 3136            // padded group stride (halves) per query row
#define NC4 392              // GSTR/8 uint4 chunks per query row
#define MARGIN 0.009f        // 2*(2^-11 RN) fp16 dot bound + fp16-bmax quant + slack

typedef _Float16 f16x8 __attribute__((ext_vector_type(8)));
typedef float f32x4 __attribute__((ext_vector_type(4)));

// ws layout (bytes)
#define WS_GP 0                        // 1563 * 32768 = 51,216,384
#define WS_QP 51216384                 // 8 * 131072   =  1,048,576
#define WS_BM 52264960                 // 2048*3136*2  = 12,845,056

__device__ inline unsigned pack_h2(float a, float b) {
    __half ha = __float2half(a), hb = __float2half(b);   // RN
    return (unsigned)*(unsigned short*)&ha | ((unsigned)*(unsigned short*)&hb << 16);
}
__device__ inline void gload_lds16(const void* gsrc, void* ldst) {
    __builtin_amdgcn_global_load_lds(
        (const __attribute__((address_space(1))) unsigned int*)gsrc,
        (__attribute__((address_space(3))) unsigned int*)ldst, 16, 0, 0);
}

#define BAR __builtin_amdgcn_s_barrier()
#define VMCNT(n) { asm volatile("s_waitcnt vmcnt(" #n ")" ::: "memory"); \
                   __builtin_amdgcn_sched_barrier(0); }

// Normalize rows, fp32->fp16 (RN), store swizzled LDS-image layout.
// Gallery: 64-row tiles; chunk (mt64*4+kt) of 512 uint4; granule (rl∈[0,64),gg)
// at rl*8 + (gg ^ (rl&7)). Queries: 256-row tiles; chunk (qt*4+kt) of 2048
// uint4, rl∈[0,256). Gallery pad rows (>=M_G) zeroed.
__global__ __launch_bounds__(256) void pack_kernel(
    const float* __restrict__ g, const float* __restrict__ q,
    uint4* __restrict__ gp, uint4* __restrict__ qp)
{
    const int b = blockIdx.x;
    const int w4 = threadIdx.x >> 6, lane = threadIdx.x & 63;
    const bool isg = b < (M_PAD / 4);
    const int row = (isg ? b : b - M_PAD / 4) * 4 + w4;
    const bool real = !isg || row < M_G;
    const float* src = isg ? g + (size_t)row * DIM : q + (size_t)row * DIM;

    float inv = 0.0f;
    if (real) {
        float4 v = ((const float4*)src)[lane];
        float ss = v.x * v.x + v.y * v.y + v.z * v.z + v.w * v.w;
        #pragma unroll
        for (int o = 32; o; o >>= 1) ss += __shfl_xor(ss, o);
        inv = 1.0f / fmaxf(sqrtf(ss), 1e-12f);
    }
    if (lane < 32) {
        uint4 w = make_uint4(0u, 0u, 0u, 0u);
        if (real) {
            float4 a = ((const float4*)src)[lane * 2];
            float4 c = ((const float4*)src)[lane * 2 + 1];
            w.x = pack_h2(a.x * inv, a.y * inv);
            w.y = pack_h2(a.z * inv, a.w * inv);
            w.z = pack_h2(c.x * inv, c.y * inv);
            w.w = pack_h2(c.z * inv, c.w * inv);
        }
        const int kt = lane >> 3, gg = lane & 7;
        if (isg) {
            int mt = row >> 6, rl = row & 63;
            gp[((size_t)mt * 4 + kt) * 512 + rl * 8 + (gg ^ (rl & 7))] = w;
        } else {
            int qt = row >> 8, rl = row & 255;
            qp[((size_t)qt * 4 + kt) * 2048 + rl * 8 + (gg ^ (rl & 7))] = w;
        }
    }
}

#define STAGE32(dstbase, src) { const uint4* s_ = (src); _Pragma("unroll") \
  for (int p_ = 0; p_ < 4; ++p_) \
    gload_lds16(s_ + p_ * 512 + tid, lds + (dstbase) + (p_ * 512 + tid) * 16); }

#define READ_BP(KT, bufbase) { _Pragma("unroll") \
  for (int nj = 0; nj < 4; ++nj) { \
    const char* p_ = lds + (bufbase) + (wc * 64 + nj * 16 + r16) * 128; \
    bR[KT][0][nj] = *(const f16x8*)(p_ + sw0); \
    bR[KT][1][nj] = *(const f16x8*)(p_ + sw1); } }

// Phase A: Q-stationary M-streaming fp16 MFMA -- the empirical best (R7):
// 256 blocks (8 qt x 32 mchunks), 512 thr = 8 waves (2m x 4n). Query frags
// (256 q x 256 k per block; 64 q per wave) live in 128 regs of the unified
// VGPR/AGPR file, fully unrolled static indices. Gallery streams as 64-row
// tiles through 2x32KB double-buffered LDS; stage(t+1) issued one full
// iteration before its counted vmcnt(4) wait (4 loads + 4 stores outstanding
// -> waits exactly the loads). bid%8 = mc%8: a chunk's 8 qt-blocks share one
// XCD's L2. Seven structural variants (R8-R14) all measured <= this one.
__global__ __launch_bounds__(512, 2) void scoreA_kernel(
    const uint4* __restrict__ gp, const uint4* __restrict__ qp,
    unsigned short* __restrict__ bmaxH)
{
    extern __shared__ char lds[];   // 65536: buf0 [0,32K) | buf1 [32K,64K)

    const int bid = blockIdx.x;
    const int qt = bid >> 5, mc = bid & 31;
    const int nt = (mc < 27) ? 49 : 48;
    const int t0 = (mc < 27) ? mc * 49 : 1323 + (mc - 27) * 48;

    const int tid = threadIdx.x;
    const int wid = tid >> 6, lane = tid & 63;
    const int wr = wid >> 2, wc = wid & 3;          // 2m x 4n wave grid
    const int r16 = lane & 15, rhi = lane >> 4;
    const int sw0 = ((rhi ^ (r16 & 7)) << 4);       // k-granule swizzle, kk=0
    const int sw1 = (((4 + rhi) ^ (r16 & 7)) << 4); // kk=1

    const uint4* qsrc = qp + (size_t)qt * 8192;

    // ---- prologue: load all B (query) fragments into registers ----
    f16x8 bR[4][2][4];
    STAGE32(0,     qsrc + 0 * 2048);
    STAGE32(32768, qsrc + 1 * 2048);
    VMCNT(4); BAR;                   // qp0 ready
    READ_BP(0, 0); BAR;
    STAGE32(0, qsrc + 2 * 2048);
    VMCNT(4); BAR;                   // qp1 ready
    READ_BP(1, 32768); BAR;
    STAGE32(32768, qsrc + 3 * 2048);
    VMCNT(4); BAR;                   // qp2 ready
    READ_BP(2, 0); BAR;
    STAGE32(0, gp + (size_t)t0 * 2048);
    VMCNT(4); BAR;                   // qp3 ready
    READ_BP(3, 32768); BAR;
    VMCNT(0); BAR;                   // A(t0) ready in buf0

    // ---- main loop: stream gallery tiles ----
    for (int t = 0; t < nt; ++t) {
        const int mtile = t0 + t;
        const int cur = (t & 1) << 15;
        const int nxt = cur ^ 32768;
        if (t + 1 < nt) STAGE32(nxt, gp + (size_t)(mtile + 1) * 2048);

        f32x4 acc[2][4];
        #pragma unroll
        for (int mi = 0; mi < 2; ++mi)
            #pragma unroll
            for (int nj = 0; nj < 4; ++nj) acc[mi][nj] = (f32x4){0.f, 0.f, 0.f, 0.f};

        #pragma unroll
        for (int kt = 0; kt < 4; ++kt) {
            #pragma unroll
            for (int kk = 0; kk < 2; ++kk) {
                const char* p_ = lds + cur + kt * 8192 + (wr * 32 + r16) * 128;
                const int sw = kk ? sw1 : sw0;
                f16x8 a0 = *(const f16x8*)(p_ + sw);
                f16x8 a1 = *(const f16x8*)(p_ + 2048 + sw);
                #pragma unroll
                for (int nj = 0; nj < 4; ++nj) {
                    acc[0][nj] = __builtin_amdgcn_mfma_f32_16x16x32_f16(
                        a0, bR[kt][kk][nj], acc[0][nj], 0, 0, 0);
                    acc[1][nj] = __builtin_amdgcn_mfma_f32_16x16x32_f16(
                        a1, bR[kt][kk][nj], acc[1][nj], 0, 0, 0);
                }
            }
        }

        // epilogue: per-q max over this wave's two 16-row frags (32-row group)
        float cm[4] = {-FLT_MAX, -FLT_MAX, -FLT_MAX, -FLT_MAX};
        #pragma unroll
        for (int mi = 0; mi < 2; ++mi)
            #pragma unroll
            for (int jj = 0; jj < 4; ++jj)
                #pragma unroll
                for (int nj = 0; nj < 4; ++nj)
                    cm[nj] = fmaxf(cm[nj], acc[mi][nj][jj]);
        // pad-safety: the last tile's wr=1 group is exactly rows >= M_G
        const bool padgrp = (mtile * 64 + wr * 32) >= M_G;
        #pragma unroll
        for (int nj = 0; nj < 4; ++nj) {
            float v = cm[nj];
            v = fmaxf(v, __shfl_xor(v, 16));
            v = fmaxf(v, __shfl_xor(v, 32));
            if (lane < 16) {
                int qn = qt * 256 + wc * 64 + nj * 16 + lane;
                __half h = __float2half(padgrp ? -65504.f : v);
                bmaxH[(size_t)qn * GSTR + mtile * 2 + wr] = *(unsigned short*)&h;
            }
        }
        // outstanding: 4 loads (oldest) + 4 stores -> VMCNT(4) = loads done
        if (t + 1 < nt) { VMCNT(4); BAR; }
    }
}

// Phase B: s1 scan + candidate collection (32-row groups, fp16 bmax,
// vectorized uint4 loads = 8 halves/load) + exact fp32 rescore with
// recomputed norms; tie-break = lowest index (np.argmax).
__global__ __launch_bounds__(256) void phaseB_kernel(
    const float* __restrict__ q, const float* __restrict__ g,
    const unsigned short* __restrict__ bmaxH,
    const int* __restrict__ cat, const int* __restrict__ shp,
    int* __restrict__ out)
{
    __shared__ __align__(16) float qrow[DIM];
    __shared__ int glist[NG];
    __shared__ int ng;
    __shared__ float smax[4];
    __shared__ float rbs[4];
    __shared__ int rbi[4];

    const int qi = blockIdx.x;
    const int tid = threadIdx.x;
    const int lane = tid & 63, wid = tid >> 6;
    const uint4* bm4 = (const uint4*)(bmaxH + (size_t)qi * GSTR);
    if (tid < 64)
        *(float4*)&qrow[tid * 4] = *(const float4*)(q + (size_t)qi * DIM + tid * 4);
    if (tid == 0) ng = 0;

    // pass 1: s1 = max over valid groups (vectorized, NG-masked)
    float m = -FLT_MAX;
    for (int c = tid; c < NC4; c += 256) {
        uint4 v = bm4[c];
        const __half* hp = (const __half*)&v;
        int base = c * 8;
        #pragma unroll
        for (int j = 0; j < 8; ++j) {
            float f = __half2float(hp[j]);
            if (base + j < NG) m = fmaxf(m, f);
        }
    }
    #pragma unroll
    for (int o = 32; o; o >>= 1) m = fmaxf(m, __shfl_xor(m, o));
    if (lane == 0) smax[wid] = m;
    __syncthreads();
    const float thr = fmaxf(fmaxf(smax[0], smax[1]), fmaxf(smax[2], smax[3])) - MARGIN;

    // pass 2: collect candidate groups (vectorized)
    for (int c = tid; c < NC4; c += 256) {
        uint4 v = bm4[c];
        const __half* hp = (const __half*)&v;
        int base = c * 8;
        #pragma unroll
        for (int j = 0; j < 8; ++j) {
            if (base + j < NG && __half2float(hp[j]) >= thr)
                glist[atomicAdd(&ng, 1)] = base + j;
        }
    }
    __syncthreads();

    float bs = -FLT_MAX;
    int bi = 0x7fffffff;
    const int r = tid >> 3, p = tid & 7;    // 32 rows x 8 dim-slices
    const int n = ng;
    for (int i = 0; i < n; ++i) {
        int mm = glist[i] * 32 + r;
        if (mm < M_G) {
            const float* grow = g + (size_t)mm * DIM + p * 32;
            const float* qr = qrow + p * 32;
            float s = 0.f, ssq = 0.f;
            #pragma unroll
            for (int jj = 0; jj < 8; ++jj) {
                float4 gv = *(const float4*)(grow + jj * 4);
                float4 qv = *(const float4*)(qr + jj * 4);
                s += gv.x * qv.x + gv.y * qv.y + gv.z * qv.z + gv.w * qv.w;
                ssq += gv.x * gv.x + gv.y * gv.y + gv.z * gv.z + gv.w * gv.w;
            }
            s += __shfl_xor(s, 1);  s += __shfl_xor(s, 2);  s += __shfl_xor(s, 4);
            ssq += __shfl_xor(ssq, 1); ssq += __shfl_xor(ssq, 2); ssq += __shfl_xor(ssq, 4);
            s *= 1.0f / fmaxf(sqrtf(ssq), 1e-12f);
            if (p == 0 && (s > bs || (s == bs && mm < bi))) { bs = s; bi = mm; }
        }
    }
    #pragma unroll
    for (int o = 1; o < 64; o <<= 1) {
        float os = __shfl_xor(bs, o);
        int oi = __shfl_xor(bi, o);
        if (os > bs || (os == bs && oi < bi)) { bs = os; bi = oi; }
    }
    if (lane == 0) { rbs[wid] = bs; rbi[wid] = bi; }
    __syncthreads();
    if (tid == 0) {
        #pragma unroll
        for (int ww = 1; ww < 4; ++ww)
            if (rbs[ww] > bs || (rbs[ww] == bs && rbi[ww] < bi)) { bs = rbs[ww]; bi = rbi[ww]; }
        out[qi] = cat[bi];
        out[N_Q + qi] = shp[bi];
    }
}

extern "C" void kernel_launch(void* const* d_in, const int* in_sizes, int n_in,
                              void* d_out, int out_size, void* d_ws, size_t ws_size,
                              hipStream_t stream) {
    const float* q = (const float*)d_in[0];    // [2048,256] fp32
    const float* g = (const float*)d_in[1];    // [100000,256] fp32
    const int* cat = (const int*)d_in[2];      // [100000] int32
    const int* shp = (const int*)d_in[3];      // [100000] int32
    int* out = (int*)d_out;                    // [2048 cat | 2048 shape] int32

    char* ws = (char*)d_ws;
    uint4* gp             = (uint4*)(ws + WS_GP);
    uint4* qp             = (uint4*)(ws + WS_QP);
    unsigned short* bmaxH = (unsigned short*)(ws + WS_BM);

    hipFuncSetAttribute((const void*)scoreA_kernel,
                        hipFuncAttributeMaxDynamicSharedMemorySize, 65536);

    pack_kernel<<<M_PAD / 4 + N_Q / 4, 256, 0, stream>>>(g, q, gp, qp);
    scoreA_kernel<<<256, 512, 65536, stream>>>(gp, qp, bmaxH);
    phaseB_kernel<<<N_Q, 256, 0, stream>>>(q, g, bmaxH, cat, shp, out);
}